// Round 9
// baseline (178.096 us; speedup 1.0000x reference)
//
#include <hip/hip_runtime.h>
#include <hip/hip_fp16.h>

#define N_NODES 50000
#define EPS 1e-6f
#define NPAD 50048      // N rounded up to 64
#define CAP 64          // fixed per-node neighbor capacity (max real deg ~45, Poisson(16))
#define NTILES (N_NODES / 16)   // 3125 16-node gather tiles
#define GGRID 1024      // persistent gather blocks (4/CU x 4 waves = 16 waves/CU)

// ---- Two-pass radix build geometry (round-13) ----
#define NBKT 512        // buckets
#define NPB 98          // nodes per bucket; NBKT*NPB = 50176 >= NPAD
#define NROWS (NBKT * NPB)
#define BCAP 2048       // per-bucket edge capacity (= 1<<11); expected 1568, +12 sigma
#define CHUNK_A 3072    // edges per bucketize block -> 261 blocks (grid contract: >=256)
#define XH8 (N_NODES * 64 / 8)   // uint4-granules of the x->half conversion

// ---------------- Workspace layout (ints then halves) ----------------
// bcur   : NBKT ints      (zeroed each call; bucket cursors / final bucket counts)
// packed : NBKT*BCAP ints ((src<<8)|dlocal, grouped by bucket)
// cnt    : NROWS ints     (per-node degree, written by rows_kernel)
// ssrc   : NROWS*64 ints  (fixed-stride per-node neighbor lists, row n at n*64)
// mean1h : NPAD*64 halves (fp16 staging of layer-1 mean)
// xh     : NPAD*64 halves (fp16 staging of x; written in bucketize)
// gh     : NPAD*64 halves (fp16 staging of layer-2 pre-gather features)
//
// NUMERICS CONTRACT (amended round-18/19): absmax pinned 0.03125 measured
// with fp16 staging of gather OPERANDS (x, mean1, g) — rounding invisible
// under f32 error floor. ADD SEQUENCE unchanged: per-node per-feature
// groups-of-4 (v0+v1)+(v2+v3) ascending, tail sequential, f32 after cvt.
//    mean = acc*dinv, dinv = 1/(deg+EPS); val = acc*dinv + b2;
//    softmax: lane-xor butterfly 8,4,2,1 then (x+z)+(y+w); (val-mx)-logf(sm).
//  - GEMMs: acc init (bias/0), fmaf ascending k, one chain per output (f32).
// SCHEDULE CONTRACT (round-6): constant-trip k-loops containing global loads
// MUST carry #pragma unroll 1 (else full unroll -> VGPR 256 -> scratch spill).
// GATHER CONTRACT (round-8): NO per-edge LDS atomics in the float gathers.
// GRID CONTRACT (round-9): latency-bound build kernels need >=256 blocks.
// MLP CONTRACT (round-11): batch row-loads in flight per wave before
// consuming (Little's law at L3 latency); adds stay in contract order.
// BUILD CONTRACT (round-13): scattered 4B global writes cost a full 64B
// HBM line each. All bulk writes must be block-coalesced.
// FUSION CONTRACT (round-14, REVERTED round-15): do not fuse gather+MLP.
// BATCH CONTRACT (round-16/17): NO predicated loads in the gather step;
// branchless: all 16 row loads issue, pad slots clamp index to row 0
// (L1-resident, never added). Adds via uniform predicates, compile-time
// indices only (no scratch), contract order.
// MACRO CONTRACT (round-17): every multi-statement macro MUST be a
// do{...}while(0) block (unbraced ADD1 under `if` -> absmax 0.25 FAIL).
// PRECISION CONTRACT (round-18): gathers are transaction-bound. fp16
// staging halves lines per row (4->2). fp16 NOT bf16 (4x tighter mantissa).
// BROADCAST CONTRACT (round-19, neutral): index broadcast via same-line
// loads == shfl broadcast in cost; keep loads (fewer DS ops).
// CONCURRENCY MODEL (round-20): gathers run at ~24 64B-lines/cyc chip-wide
// = MSHR(~64/CU) / L3-latency(~550cyc). Headroom exists only via keeping
// MSHRs full: persistent grid-stride blocks (GGRID=1024, 16 waves/CU),
// no launch churn. Floor estimate ~20us per fp16 gather.

#define COMP(v, j) ((j) == 0 ? (v).x : (j) == 1 ? (v).y : (j) == 2 ? (v).z : (v).w)

__device__ __forceinline__ float4 h4_to_f4(uint2 u) {
  __half2 h0 = *reinterpret_cast<__half2*>(&u.x);
  __half2 h1 = *reinterpret_cast<__half2*>(&u.y);
  float2 f0 = __half22float2(h0);
  float2 f1 = __half22float2(h1);
  float4 r; r.x = f0.x; r.y = f0.y; r.z = f1.x; r.w = f1.y;
  return r;
}

// ---- Pass A: partition edges into 512 buckets of 98 nodes ----
// (also converts x -> xh fp16 staging, grid-stride; consumed 2 dispatches later)
__global__ __launch_bounds__(256) void bucketize_kernel(
    const int* __restrict__ src, const int* __restrict__ dst,
    int* __restrict__ bcur, int* __restrict__ packed,
    const float* __restrict__ x, __half* __restrict__ xh, int E) {
  __shared__ int lcnt[NBKT];
  __shared__ int lbase[NBKT];
  int t = threadIdx.x;

  // x -> xh conversion (independent streaming work, no sync interplay)
  for (int i = blockIdx.x * 256 + t; i < XH8; i += gridDim.x * 256) {
    float4 a = ((const float4*)x)[2 * i];
    float4 b = ((const float4*)x)[2 * i + 1];
    __half2 h0 = __floats2half2_rn(a.x, a.y);
    __half2 h1 = __floats2half2_rn(a.z, a.w);
    __half2 h2 = __floats2half2_rn(b.x, b.y);
    __half2 h3 = __floats2half2_rn(b.z, b.w);
    uint4 o;
    o.x = *(unsigned int*)&h0; o.y = *(unsigned int*)&h1;
    o.z = *(unsigned int*)&h2; o.w = *(unsigned int*)&h3;
    ((uint4*)xh)[i] = o;
  }

  lcnt[t] = 0; lcnt[t + 256] = 0;
  __syncthreads();
  int base = blockIdx.x * CHUNK_A;
  int end = base + CHUNK_A; if (end > E) end = E;
  for (int e = base + t; e < end; e += 256) atomicAdd(&lcnt[dst[e] / NPB], 1);
  __syncthreads();
  {  // one global reservation per touched bucket (thread t owns buckets t, t+256)
    int c0 = lcnt[t], c1 = lcnt[t + 256];
    lbase[t]       = c0 ? atomicAdd(&bcur[t], c0) : 0;
    lbase[t + 256] = c1 ? atomicAdd(&bcur[t + 256], c1) : 0;
    lcnt[t] = 0; lcnt[t + 256] = 0;  // reuse as local cursors (own slots only)
  }
  __syncthreads();
  for (int e = base + t; e < end; e += 256) {
    int d = dst[e];
    int b = d / NPB;                 // compile-time magic-mul division
    int pos = lbase[b] + atomicAdd(&lcnt[b], 1);
    if (pos < BCAP)                  // guard: never OOB
      packed[(b << 11) + pos] = (src[e] << 8) | (d - b * NPB);
  }
}

// ---- Pass B: materialize per-node rows from LDS image, full-line stores ----
__global__ __launch_bounds__(256) void rows_kernel(
    const int* __restrict__ bcur, const int* __restrict__ packed,
    int* __restrict__ cnt, int* __restrict__ ssrc) {
  __shared__ int lout[NPB * 64];   // 25088 B bucket row image (garbage slots never read)
  __shared__ int lcnt[NPB];
  int t = threadIdx.x;
  int b = blockIdx.x;
  if (t < NPB) lcnt[t] = 0;
  __syncthreads();
  int count = bcur[b]; if (count > BCAP) count = BCAP;
  const int* pk = packed + (b << 11);
  for (int i = t; i < count; i += 256) {
    int p = pk[i];
    int dl = p & 0xff;
    int pos = atomicAdd(&lcnt[dl], 1);
    if (pos < CAP) lout[(dl << 6) + pos] = p >> 8;
  }
  __syncthreads();
  int4* d4 = (int4*)(ssrc + (size_t)b * (NPB * 64));
  const int4* s4 = (const int4*)lout;
  for (int i = t; i < NPB * 16; i += 256) d4[i] = s4[i];
  if (t < NPB) {
    int c = lcnt[t]; if (c > CAP) c = CAP;
    cnt[b * NPB + t] = c;
  }
}

// Quad add in contract order (per component: one quad at a time, ascending).
#define QADD(V0, V1, V2, V3) do {                                         \
    acc.x += ((V0).x + (V1).x) + ((V2).x + (V3).x);                       \
    acc.y += ((V0).y + (V1).y) + ((V2).y + (V3).y);                       \
    acc.z += ((V0).z + (V1).z) + ((V2).z + (V3).z);                       \
    acc.w += ((V0).w + (V1).w) + ((V2).w + (V3).w);                       \
  } while (0)

#define ADD1(V) do {                                                      \
    acc.x += (V).x; acc.y += (V).y; acc.z += (V).z; acc.w += (V).w;       \
  } while (0)

// One gather step over edges [base, base+rem), rem<=16, fp16 source rows.
// Index broadcast via same-address loads (one 64B ssrc line per subgroup,
// L1 broadcast). Pad slots clamp index to row 0 after the load. All 16
// row loads issue branchlessly; convert-to-f32 per quad; contract adds.
#define GATHER_STEP_H(SRCPTR)                                             \
  {                                                                       \
    int rem = e - base; if (rem > 16) rem = 16;                           \
    int s[16];                                                            \
    _Pragma("unroll")                                                     \
    for (int j = 0; j < 16; j++) s[j] = ssrc[base + j];                   \
    _Pragma("unroll")                                                     \
    for (int j = 0; j < 16; j++) { if (j >= rem) s[j] = 0; }              \
    uint2 v[16];                                                          \
    _Pragma("unroll")                                                     \
    for (int j = 0; j < 16; j++)                                          \
      v[j] = ((const uint2*)((SRCPTR) + (size_t)s[j] * 64))[l16];         \
    int rq = rem >> 2, rr = rem & 3;                                      \
    _Pragma("unroll")                                                     \
    for (int q = 0; q < 4; q++) {                                         \
      if (q < rq) {                                                       \
        float4 f0 = h4_to_f4(v[4 * q]);                                   \
        float4 f1 = h4_to_f4(v[4 * q + 1]);                               \
        float4 f2 = h4_to_f4(v[4 * q + 2]);                               \
        float4 f3 = h4_to_f4(v[4 * q + 3]);                               \
        QADD(f0, f1, f2, f3);                                             \
      }                                                                   \
    }                                                                     \
    _Pragma("unroll")                                                     \
    for (int q = 0; q < 4; q++) {                                         \
      if (q == rq && rr > 0) {                                            \
        float4 f0 = h4_to_f4(v[4 * q]);                                   \
        ADD1(f0);                                                         \
        if (rr > 1) { float4 f1 = h4_to_f4(v[4 * q + 1]); ADD1(f1); }     \
        if (rr > 2) { float4 f2 = h4_to_f4(v[4 * q + 2]); ADD1(f2); }     \
      }                                                                   \
    }                                                                     \
  }

// ---- Gather 1 (persistent grid-stride): mean1h[n] = mean of xh[neighbors] ----
__global__ __launch_bounds__(256) void gather1_kernel(
    const __half* __restrict__ xh, const int* __restrict__ cnt,
    const int* __restrict__ ssrc, __half* __restrict__ mean1h) {
  int t = threadIdx.x;
  int lane = t & 63;
  int sub = lane >> 4;
  int l16 = lane & 15;
  int wv = t >> 6;
  for (int tile = blockIdx.x; tile < NTILES; tile += GGRID) {
    int node = tile * 16 + (wv << 2) + sub;
    int b = node << 6;
    int e = b + cnt[node];
    float4 acc = {0.f, 0.f, 0.f, 0.f};
    for (int base = b; base < e; base += 16) {
      GATHER_STEP_H(xh)
    }
    float dinv = 1.0f / ((float)(e - b) + EPS);
    __half2 p0 = __floats2half2_rn(acc.x * dinv, acc.y * dinv);
    __half2 p1 = __floats2half2_rn(acc.z * dinv, acc.w * dinv);
    uint2 o;
    o.x = *(unsigned int*)&p0; o.y = *(unsigned int*)&p1;
    ((uint2*)(mean1h + (size_t)node * 64))[l16] = o;
  }
}

// ---- Fused MLP (round-7 GEMM cores; fp16 in, fp16 out) ----
__global__ __launch_bounds__(256, 3) void mlp_fused_kernel(
    const __half* __restrict__ mean1h, const float* __restrict__ W1,
    const float* __restrict__ b1, const float* __restrict__ W2,
    __half* __restrict__ gh) {
  __shared__ float sM[64][68];
  __shared__ float sH[64][132];
  int t = threadIdx.x;
  int row0 = blockIdx.x * 64;

  {
    const uint2* M2 = (const uint2*)(mean1h + (size_t)row0 * 64);
#pragma unroll
    for (int i = 0; i < 4; i++) {
      int idx = t + 256 * i;
      float4 f = h4_to_f4(M2[idx]);
      *(float4*)&sM[idx >> 4][(idx & 15) << 2] = f;
    }
  }
  __syncthreads();

  int tc = t & 15;
  int tr = t >> 4;

  {  // GEMM1 + relu -> sH
    int c = tc << 3;
    int r = tr << 2;
    float acc[4][8];
    float4 bA = *(const float4*)(b1 + c);
    float4 bB = *(const float4*)(b1 + c + 4);
#pragma unroll
    for (int i = 0; i < 4; i++) {
      acc[i][0] = bA.x; acc[i][1] = bA.y; acc[i][2] = bA.z; acc[i][3] = bA.w;
      acc[i][4] = bB.x; acc[i][5] = bB.y; acc[i][6] = bB.z; acc[i][7] = bB.w;
    }
#pragma unroll 1
    for (int k = 0; k < 64; k += 4) {
      float4 a[4];
#pragma unroll
      for (int i = 0; i < 4; i++) a[i] = *(const float4*)&sM[r + i][k];
      float4 wA[4], wB[4];
#pragma unroll
      for (int j = 0; j < 4; j++) {
        const float* wrow = W1 + (size_t)(k + j) * 128 + c;
        wA[j] = *(const float4*)wrow;
        wB[j] = *(const float4*)(wrow + 4);
      }
#pragma unroll
      for (int j = 0; j < 4; j++) {
#pragma unroll
        for (int i = 0; i < 4; i++) {
          float av = COMP(a[i], j);
          acc[i][0] = fmaf(av, wA[j].x, acc[i][0]);
          acc[i][1] = fmaf(av, wA[j].y, acc[i][1]);
          acc[i][2] = fmaf(av, wA[j].z, acc[i][2]);
          acc[i][3] = fmaf(av, wA[j].w, acc[i][3]);
          acc[i][4] = fmaf(av, wB[j].x, acc[i][4]);
          acc[i][5] = fmaf(av, wB[j].y, acc[i][5]);
          acc[i][6] = fmaf(av, wB[j].z, acc[i][6]);
          acc[i][7] = fmaf(av, wB[j].w, acc[i][7]);
        }
      }
    }
#pragma unroll
    for (int i = 0; i < 4; i++) {
      float4 h0, h1v;
      h0.x = fmaxf(acc[i][0], 0.f); h0.y = fmaxf(acc[i][1], 0.f);
      h0.z = fmaxf(acc[i][2], 0.f); h0.w = fmaxf(acc[i][3], 0.f);
      h1v.x = fmaxf(acc[i][4], 0.f); h1v.y = fmaxf(acc[i][5], 0.f);
      h1v.z = fmaxf(acc[i][6], 0.f); h1v.w = fmaxf(acc[i][7], 0.f);
      *(float4*)&sH[r + i][c] = h0;
      *(float4*)&sH[r + i][c + 4] = h1v;
    }
  }
  __syncthreads();

  {  // GEMM2 -> gh (fp16 store)
    int c = tc << 2;
    int r = tr << 2;
    float acc[4][4];
#pragma unroll
    for (int i = 0; i < 4; i++)
      acc[i][0] = acc[i][1] = acc[i][2] = acc[i][3] = 0.f;
#pragma unroll 1
    for (int k = 0; k < 128; k += 4) {
      float4 a[4];
#pragma unroll
      for (int i = 0; i < 4; i++) a[i] = *(const float4*)&sH[r + i][k];
      float4 w[4];
#pragma unroll
      for (int j = 0; j < 4; j++)
        w[j] = *(const float4*)(W2 + (size_t)(k + j) * 64 + c);
#pragma unroll
      for (int j = 0; j < 4; j++) {
#pragma unroll
        for (int i = 0; i < 4; i++) {
          float av = COMP(a[i], j);
          acc[i][0] = fmaf(av, w[j].x, acc[i][0]);
          acc[i][1] = fmaf(av, w[j].y, acc[i][1]);
          acc[i][2] = fmaf(av, w[j].z, acc[i][2]);
          acc[i][3] = fmaf(av, w[j].w, acc[i][3]);
        }
      }
    }
#pragma unroll
    for (int i = 0; i < 4; i++) {
      int row = row0 + r + i;
      if (row < N_NODES) {
        __half2 p0 = __floats2half2_rn(acc[i][0], acc[i][1]);
        __half2 p1 = __floats2half2_rn(acc[i][2], acc[i][3]);
        uint2 o;
        o.x = *(unsigned int*)&p0; o.y = *(unsigned int*)&p1;
        *(uint2*)(gh + (size_t)row * 64 + c) = o;
      }
    }
  }
}

// ---- Gather 2 (persistent grid-stride) + bias + log_softmax ----
__global__ __launch_bounds__(256) void gather2_kernel(
    const __half* __restrict__ gh, const int* __restrict__ cnt,
    const int* __restrict__ ssrc, const float* __restrict__ b2,
    float* __restrict__ out) {
  int t = threadIdx.x;
  int lane = t & 63;
  int sub = lane >> 4;
  int l16 = lane & 15;
  int wv = t >> 6;
  for (int tile = blockIdx.x; tile < NTILES; tile += GGRID) {
    int node = tile * 16 + (wv << 2) + sub;
    int b = node << 6;
    int e = b + cnt[node];
    float4 acc = {0.f, 0.f, 0.f, 0.f};
    for (int base = b; base < e; base += 16) {
      GATHER_STEP_H(gh)
    }
    float dinv = 1.0f / ((float)(e - b) + EPS);
    float4 b2v = ((const float4*)b2)[l16];
    float4 val;
    val.x = acc.x * dinv + b2v.x;
    val.y = acc.y * dinv + b2v.y;
    val.z = acc.z * dinv + b2v.z;
    val.w = acc.w * dinv + b2v.w;

    float4 m = val;
#pragma unroll
    for (int o = 8; o > 0; o >>= 1) {
      m.x = fmaxf(m.x, __shfl_xor(m.x, o, 64));
      m.y = fmaxf(m.y, __shfl_xor(m.y, o, 64));
      m.z = fmaxf(m.z, __shfl_xor(m.z, o, 64));
      m.w = fmaxf(m.w, __shfl_xor(m.w, o, 64));
    }
    float mx = fmaxf(fmaxf(m.x, m.z), fmaxf(m.y, m.w));

    float4 ex;
    ex.x = __expf(val.x - mx);
    ex.y = __expf(val.y - mx);
    ex.z = __expf(val.z - mx);
    ex.w = __expf(val.w - mx);
#pragma unroll
    for (int o = 8; o > 0; o >>= 1) {
      ex.x += __shfl_xor(ex.x, o, 64);
      ex.y += __shfl_xor(ex.y, o, 64);
      ex.z += __shfl_xor(ex.z, o, 64);
      ex.w += __shfl_xor(ex.w, o, 64);
    }
    float sm = (ex.x + ex.z) + (ex.y + ex.w);

    float ls = logf(sm);
    float4 o4;
    o4.x = (val.x - mx) - ls;
    o4.y = (val.y - mx) - ls;
    o4.z = (val.z - mx) - ls;
    o4.w = (val.w - mx) - ls;
    ((float4*)(out + (size_t)node * 64))[l16] = o4;
  }
}

extern "C" void kernel_launch(void* const* d_in, const int* in_sizes, int n_in,
                              void* d_out, int out_size, void* d_ws, size_t ws_size,
                              hipStream_t stream) {
  const float* x   = (const float*)d_in[0];
  const int*   src = (const int*)d_in[1];
  const int*   dst = (const int*)d_in[2];
  const float* W1  = (const float*)d_in[3];
  const float* b1  = (const float*)d_in[4];
  const float* W2  = (const float*)d_in[5];
  const float* b2  = (const float*)d_in[6];
  float* out = (float*)d_out;
  int E = in_sizes[1];

  int* bcur   = (int*)d_ws;                         // NBKT
  int* packed = bcur + NBKT;                        // NBKT*BCAP
  int* cnt    = packed + (size_t)NBKT * BCAP;       // NROWS
  int* ssrc   = cnt + NROWS;                        // NROWS*64
  __half* mean1h = (__half*)(ssrc + (size_t)NROWS * 64); // NPAD*64 halves
  __half* xh   = mean1h + (size_t)NPAD * 64;             // NPAD*64 halves
  __half* gh   = xh + (size_t)NPAD * 64;                 // NPAD*64 halves

  hipMemsetAsync(bcur, 0, NBKT * sizeof(int), stream);
  bucketize_kernel<<<(E + CHUNK_A - 1) / CHUNK_A, 256, 0, stream>>>(
      src, dst, bcur, packed, x, xh, E);
  rows_kernel<<<NBKT, 256, 0, stream>>>(bcur, packed, cnt, ssrc);
  gather1_kernel<<<GGRID, 256, 0, stream>>>(xh, cnt, ssrc, mean1h);
  mlp_fused_kernel<<<NPAD / 64, 256, 0, stream>>>(mean1h, W1, b1, W2, gh);
  gather2_kernel<<<GGRID, 256, 0, stream>>>(gh, cnt, ssrc, b2, out);
}

// Round 10
// 159.899 us; speedup vs baseline: 1.1138x; 1.1138x over previous
//
#include <hip/hip_runtime.h>
#include <hip/hip_fp16.h>

#define N_NODES 50000
#define EPS 1e-6f
#define NPAD 50048      // N rounded up to 64
#define CAP 64          // fixed per-node neighbor capacity (max real deg ~45, Poisson(16))

// ---- Two-pass radix build geometry (round-13) ----
#define NBKT 512        // buckets
#define NPB 98          // nodes per bucket; NBKT*NPB = 50176 >= NPAD
#define NROWS (NBKT * NPB)
#define BCAP 2048       // per-bucket edge capacity (= 1<<11); expected 1568, +12 sigma
#define CHUNK_A 3072    // edges per bucketize block -> 261 blocks (grid contract: >=256)
#define XH8 (N_NODES * 64 / 8)   // uint4-granules of the x->half conversion

// ---------------- Workspace layout (ints then halves) ----------------
// bcur   : NBKT ints      (zeroed each call)
// packed : NBKT*BCAP ints ((src<<8)|dlocal, grouped by bucket)
// cnt    : NROWS ints     (per-node degree)
// ssrc   : NROWS*64 ints  (fixed-stride per-node neighbor lists)
// mean1h : NPAD*64 halves (fp16 staging of layer-1 mean)
// xh     : NPAD*64 halves (fp16 staging of x)
// gh     : NPAD*64 halves (fp16 staging of layer-2 pre-gather features)
//
// NUMERICS CONTRACT (r18/19/21): absmax pinned 0.03125 (= 1 ulp of the
// bf16 output comparison). fp16 staging of gather operands (x, mean1, g)
// measured-invisible. Round-21 adds fp16 W1/W2/H with f32-accum MFMA GEMMs
// (hardware-defined in-MFMA add order replaces the fmaf chain; predicted
// extra error ~1e-2 << 0.093 threshold). Gather ADD SEQUENCE unchanged:
// groups-of-4 (v0+v1)+(v2+v3) ascending, tail sequential, f32 after cvt.
//    mean = acc*dinv, dinv = 1/(deg+EPS); val = acc*dinv + b2;
//    softmax: lane-xor butterfly 8,4,2,1 then (x+z)+(y+w); (val-mx)-logf(sm).
// MFMA LAYOUT (round-21, per m89/m92/m97-verified pattern): A/B frags are
// contiguous-k: lane holds k=(lane>>4)*8+i via ds_read_b128 from row-major
// [m][k] / [n][k] (transposed-B) LDS tiles; C/D col=lane&15,
// row=(lane>>4)*4+reg. LDS tiles padded to stride%32banks==4.
// SCHEDULE CONTRACT (round-6): constant-trip k-loops with global loads
// carry #pragma unroll 1 (f32 path; MFMA loops are LDS-only, exempt).
// GATHER CONTRACT (round-8): NO per-edge LDS atomics in float gathers.
// GRID CONTRACT (round-9/20): build kernels >=256 blocks; gathers use
// per-tile grids (3125) — persistent grid-stride REGRESSED (round-20).
// BUILD CONTRACT (round-13): no scattered 4B global writes; bulk writes
// block-coalesced via LDS staging.
// FUSION CONTRACT (round-14): do not fuse gather+MLP.
// BATCH CONTRACT (round-16/17): branchless 16-load gather step; pad slots
// clamp index to row 0; uniform-predicate adds, compile-time indices.
// MACRO CONTRACT (round-17): multi-statement macros are do{...}while(0).
// PRECISION CONTRACT (round-18): fp16 staging (NOT bf16).
// BROADCAST CONTRACT (round-19, neutral): same-line index loads kept.

#define COMP(v, j) ((j) == 0 ? (v).x : (j) == 1 ? (v).y : (j) == 2 ? (v).z : (v).w)

typedef _Float16 half8 __attribute__((ext_vector_type(8)));
typedef float floatx4 __attribute__((ext_vector_type(4)));

__device__ __forceinline__ float4 h4_to_f4(uint2 u) {
  __half2 h0 = *reinterpret_cast<__half2*>(&u.x);
  __half2 h1 = *reinterpret_cast<__half2*>(&u.y);
  float2 f0 = __half22float2(h0);
  float2 f1 = __half22float2(h1);
  float4 r; r.x = f0.x; r.y = f0.y; r.z = f1.x; r.w = f1.y;
  return r;
}

// ---- Pass A: partition edges into 512 buckets of 98 nodes ----
// (also converts x -> xh fp16 staging, grid-stride)
__global__ __launch_bounds__(256) void bucketize_kernel(
    const int* __restrict__ src, const int* __restrict__ dst,
    int* __restrict__ bcur, int* __restrict__ packed,
    const float* __restrict__ x, __half* __restrict__ xh, int E) {
  __shared__ int lcnt[NBKT];
  __shared__ int lbase[NBKT];
  int t = threadIdx.x;

  for (int i = blockIdx.x * 256 + t; i < XH8; i += gridDim.x * 256) {
    float4 a = ((const float4*)x)[2 * i];
    float4 b = ((const float4*)x)[2 * i + 1];
    __half2 h0 = __floats2half2_rn(a.x, a.y);
    __half2 h1 = __floats2half2_rn(a.z, a.w);
    __half2 h2 = __floats2half2_rn(b.x, b.y);
    __half2 h3 = __floats2half2_rn(b.z, b.w);
    uint4 o;
    o.x = *(unsigned int*)&h0; o.y = *(unsigned int*)&h1;
    o.z = *(unsigned int*)&h2; o.w = *(unsigned int*)&h3;
    ((uint4*)xh)[i] = o;
  }

  lcnt[t] = 0; lcnt[t + 256] = 0;
  __syncthreads();
  int base = blockIdx.x * CHUNK_A;
  int end = base + CHUNK_A; if (end > E) end = E;
  for (int e = base + t; e < end; e += 256) atomicAdd(&lcnt[dst[e] / NPB], 1);
  __syncthreads();
  {
    int c0 = lcnt[t], c1 = lcnt[t + 256];
    lbase[t]       = c0 ? atomicAdd(&bcur[t], c0) : 0;
    lbase[t + 256] = c1 ? atomicAdd(&bcur[t + 256], c1) : 0;
    lcnt[t] = 0; lcnt[t + 256] = 0;
  }
  __syncthreads();
  for (int e = base + t; e < end; e += 256) {
    int d = dst[e];
    int b = d / NPB;
    int pos = lbase[b] + atomicAdd(&lcnt[b], 1);
    if (pos < BCAP)
      packed[(b << 11) + pos] = (src[e] << 8) | (d - b * NPB);
  }
}

// ---- Pass B: materialize per-node rows from LDS image, full-line stores ----
__global__ __launch_bounds__(256) void rows_kernel(
    const int* __restrict__ bcur, const int* __restrict__ packed,
    int* __restrict__ cnt, int* __restrict__ ssrc) {
  __shared__ int lout[NPB * 64];
  __shared__ int lcnt[NPB];
  int t = threadIdx.x;
  int b = blockIdx.x;
  if (t < NPB) lcnt[t] = 0;
  __syncthreads();
  int count = bcur[b]; if (count > BCAP) count = BCAP;
  const int* pk = packed + (b << 11);
  for (int i = t; i < count; i += 256) {
    int p = pk[i];
    int dl = p & 0xff;
    int pos = atomicAdd(&lcnt[dl], 1);
    if (pos < CAP) lout[(dl << 6) + pos] = p >> 8;
  }
  __syncthreads();
  int4* d4 = (int4*)(ssrc + (size_t)b * (NPB * 64));
  const int4* s4 = (const int4*)lout;
  for (int i = t; i < NPB * 16; i += 256) d4[i] = s4[i];
  if (t < NPB) {
    int c = lcnt[t]; if (c > CAP) c = CAP;
    cnt[b * NPB + t] = c;
  }
}

// Quad add in contract order (per component: one quad at a time, ascending).
#define QADD(V0, V1, V2, V3) do {                                         \
    acc.x += ((V0).x + (V1).x) + ((V2).x + (V3).x);                       \
    acc.y += ((V0).y + (V1).y) + ((V2).y + (V3).y);                       \
    acc.z += ((V0).z + (V1).z) + ((V2).z + (V3).z);                       \
    acc.w += ((V0).w + (V1).w) + ((V2).w + (V3).w);                       \
  } while (0)

#define ADD1(V) do {                                                      \
    acc.x += (V).x; acc.y += (V).y; acc.z += (V).z; acc.w += (V).w;       \
  } while (0)

#define GATHER_STEP_H(SRCPTR)                                             \
  {                                                                       \
    int rem = e - base; if (rem > 16) rem = 16;                           \
    int s[16];                                                            \
    _Pragma("unroll")                                                     \
    for (int j = 0; j < 16; j++) s[j] = ssrc[base + j];                   \
    _Pragma("unroll")                                                     \
    for (int j = 0; j < 16; j++) { if (j >= rem) s[j] = 0; }              \
    uint2 v[16];                                                          \
    _Pragma("unroll")                                                     \
    for (int j = 0; j < 16; j++)                                          \
      v[j] = ((const uint2*)((SRCPTR) + (size_t)s[j] * 64))[l16];         \
    int rq = rem >> 2, rr = rem & 3;                                      \
    _Pragma("unroll")                                                     \
    for (int q = 0; q < 4; q++) {                                         \
      if (q < rq) {                                                       \
        float4 f0 = h4_to_f4(v[4 * q]);                                   \
        float4 f1 = h4_to_f4(v[4 * q + 1]);                               \
        float4 f2 = h4_to_f4(v[4 * q + 2]);                               \
        float4 f3 = h4_to_f4(v[4 * q + 3]);                               \
        QADD(f0, f1, f2, f3);                                             \
      }                                                                   \
    }                                                                     \
    _Pragma("unroll")                                                     \
    for (int q = 0; q < 4; q++) {                                         \
      if (q == rq && rr > 0) {                                            \
        float4 f0 = h4_to_f4(v[4 * q]);                                   \
        ADD1(f0);                                                         \
        if (rr > 1) { float4 f1 = h4_to_f4(v[4 * q + 1]); ADD1(f1); }     \
        if (rr > 2) { float4 f2 = h4_to_f4(v[4 * q + 2]); ADD1(f2); }     \
      }                                                                   \
    }                                                                     \
  }

// ---- Gather 1: mean1h[n] = mean of xh[neighbors] (f32 accumulate, fp16 store) ----
__global__ __launch_bounds__(256) void gather1_kernel(
    const __half* __restrict__ xh, const int* __restrict__ cnt,
    const int* __restrict__ ssrc, __half* __restrict__ mean1h) {
  int t = threadIdx.x;
  int lane = t & 63;
  int sub = lane >> 4;
  int l16 = lane & 15;
  int node = blockIdx.x * 16 + ((t >> 6) << 2) + sub;
  int b = node << 6;
  int e = b + cnt[node];
  float4 acc = {0.f, 0.f, 0.f, 0.f};
  for (int base = b; base < e; base += 16) {
    GATHER_STEP_H(xh)
  }
  float dinv = 1.0f / ((float)(e - b) + EPS);
  __half2 p0 = __floats2half2_rn(acc.x * dinv, acc.y * dinv);
  __half2 p1 = __floats2half2_rn(acc.z * dinv, acc.w * dinv);
  uint2 o;
  o.x = *(unsigned int*)&p0; o.y = *(unsigned int*)&p1;
  ((uint2*)(mean1h + (size_t)node * 64))[l16] = o;
}

// ---- MFMA MLP: GEMM1(64x64x128)+relu -> GEMM2(64x128x64), fp16 out ----
__global__ __launch_bounds__(256) void mlp_mfma_kernel(
    const __half* __restrict__ mean1h, const float* __restrict__ W1,
    const float* __restrict__ b1, const float* __restrict__ W2,
    __half* __restrict__ gh) {
  // LDS carve: sM[64][72] 9216B | sW1T[128][72] 18432B | sH[64][136] 17408B
  //            | sW2T[64][136] 17408B = 62464B. sG[64][64] aliases sM.
  __shared__ __align__(16) char smem[62464];
  __half (*sM)[72]    = (__half(*)[72])smem;
  __half (*sW1T)[72]  = (__half(*)[72])(smem + 9216);
  __half (*sH)[136]   = (__half(*)[136])(smem + 27648);
  __half (*sW2T)[136] = (__half(*)[136])(smem + 45056);
  __half (*sG)[64]    = (__half(*)[64])smem;

  int t = threadIdx.x;
  int row0 = blockIdx.x * 64;

  {  // stage mean rows (fp16 as-is): 512 uint4
    const uint4* M4 = (const uint4*)(mean1h + (size_t)row0 * 64);
#pragma unroll
    for (int i = 0; i < 2; i++) {
      int idx = t + 256 * i;
      uint4 v = M4[idx];
      *(uint4*)&sM[idx >> 3][(idx & 7) * 8] = v;
    }
  }
#pragma unroll
  for (int i = 0; i < 8; i++) {  // W1[64][128] f32 -> sW1T[c][k] fp16
    int idx = t + 256 * i;
    int k = idx >> 5, c4 = (idx & 31) * 4;
    float4 w = *(const float4*)(W1 + (size_t)k * 128 + c4);
    sW1T[c4 + 0][k] = __float2half(w.x);
    sW1T[c4 + 1][k] = __float2half(w.y);
    sW1T[c4 + 2][k] = __float2half(w.z);
    sW1T[c4 + 3][k] = __float2half(w.w);
  }
#pragma unroll
  for (int i = 0; i < 8; i++) {  // W2[128][64] f32 -> sW2T[c][k] fp16
    int idx = t + 256 * i;
    int k = idx >> 4, c4 = (idx & 15) * 4;
    float4 w = *(const float4*)(W2 + (size_t)k * 64 + c4);
    sW2T[c4 + 0][k] = __float2half(w.x);
    sW2T[c4 + 1][k] = __float2half(w.y);
    sW2T[c4 + 2][k] = __float2half(w.z);
    sW2T[c4 + 3][k] = __float2half(w.w);
  }
  __syncthreads();

  int l = t & 63, wv = t >> 6;
  int l16 = l & 15, lg = l >> 4;

  {  // GEMM1: wave wv owns col-tiles {2wv,2wv+1} x row-tiles 0..3, K=64
    floatx4 acc[4][2];
#pragma unroll
    for (int tc = 0; tc < 2; tc++) {
      float bias = b1[(2 * wv + tc) * 16 + l16];
#pragma unroll
      for (int tr = 0; tr < 4; tr++)
        acc[tr][tc] = (floatx4){bias, bias, bias, bias};
    }
#pragma unroll
    for (int kb = 0; kb < 2; kb++) {
      half8 a[4], bf[2];
#pragma unroll
      for (int tr = 0; tr < 4; tr++)
        a[tr] = *(const half8*)&sM[tr * 16 + l16][kb * 32 + lg * 8];
#pragma unroll
      for (int tc = 0; tc < 2; tc++)
        bf[tc] = *(const half8*)&sW1T[(2 * wv + tc) * 16 + l16][kb * 32 + lg * 8];
#pragma unroll
      for (int tc = 0; tc < 2; tc++)
#pragma unroll
        for (int tr = 0; tr < 4; tr++)
          acc[tr][tc] = __builtin_amdgcn_mfma_f32_16x16x32_f16(
              a[tr], bf[tc], acc[tr][tc], 0, 0, 0);
    }
#pragma unroll
    for (int tc = 0; tc < 2; tc++)
#pragma unroll
      for (int tr = 0; tr < 4; tr++)
#pragma unroll
        for (int r = 0; r < 4; r++) {
          float h = fmaxf(acc[tr][tc][r], 0.f);
          sH[tr * 16 + lg * 4 + r][(2 * wv + tc) * 16 + l16] = __float2half(h);
        }
  }
  __syncthreads();

  {  // GEMM2: wave wv owns row-tile wv x col-tiles 0..3, K=128
    floatx4 acc[4];
#pragma unroll
    for (int tc = 0; tc < 4; tc++) acc[tc] = (floatx4){0.f, 0.f, 0.f, 0.f};
    half8 a[4];
#pragma unroll
    for (int kb = 0; kb < 4; kb++)
      a[kb] = *(const half8*)&sH[wv * 16 + l16][kb * 32 + lg * 8];
#pragma unroll
    for (int tc = 0; tc < 4; tc++) {
#pragma unroll
      for (int kb = 0; kb < 4; kb++) {
        half8 bf = *(const half8*)&sW2T[tc * 16 + l16][kb * 32 + lg * 8];
        acc[tc] = __builtin_amdgcn_mfma_f32_16x16x32_f16(a[kb], bf, acc[tc], 0, 0, 0);
      }
    }
    // sG aliases sM — sM is dead after GEMM1's closing barrier.
#pragma unroll
    for (int tc = 0; tc < 4; tc++)
#pragma unroll
      for (int r = 0; r < 4; r++)
        sG[wv * 16 + lg * 4 + r][tc * 16 + l16] = __float2half(acc[tc][r]);
  }
  __syncthreads();

  // coalesced copy sG -> gh (8B granules), guard tail rows
#pragma unroll
  for (int i = 0; i < 4; i++) {
    int idx = t + 256 * i;            // 0..1023
    int row = idx >> 4, c4 = (idx & 15) * 4;
    if (row0 + row < N_NODES)
      *(uint2*)(gh + (size_t)(row0 + row) * 64 + c4) = *(uint2*)&sG[row][c4];
  }
}

// ---- Gather 2 + bias + log_softmax (fp16 source, f32 math) ----
__global__ __launch_bounds__(256) void gather2_kernel(
    const __half* __restrict__ gh, const int* __restrict__ cnt,
    const int* __restrict__ ssrc, const float* __restrict__ b2,
    float* __restrict__ out) {
  int t = threadIdx.x;
  int lane = t & 63;
  int sub = lane >> 4;
  int l16 = lane & 15;
  int node = blockIdx.x * 16 + ((t >> 6) << 2) + sub;
  int b = node << 6;
  int e = b + cnt[node];
  float4 acc = {0.f, 0.f, 0.f, 0.f};
  for (int base = b; base < e; base += 16) {
    GATHER_STEP_H(gh)
  }
  float dinv = 1.0f / ((float)(e - b) + EPS);
  float4 b2v = ((const float4*)b2)[l16];
  float4 val;
  val.x = acc.x * dinv + b2v.x;
  val.y = acc.y * dinv + b2v.y;
  val.z = acc.z * dinv + b2v.z;
  val.w = acc.w * dinv + b2v.w;

  float4 m = val;
#pragma unroll
  for (int o = 8; o > 0; o >>= 1) {
    m.x = fmaxf(m.x, __shfl_xor(m.x, o, 64));
    m.y = fmaxf(m.y, __shfl_xor(m.y, o, 64));
    m.z = fmaxf(m.z, __shfl_xor(m.z, o, 64));
    m.w = fmaxf(m.w, __shfl_xor(m.w, o, 64));
  }
  float mx = fmaxf(fmaxf(m.x, m.z), fmaxf(m.y, m.w));

  float4 ex;
  ex.x = __expf(val.x - mx);
  ex.y = __expf(val.y - mx);
  ex.z = __expf(val.z - mx);
  ex.w = __expf(val.w - mx);
#pragma unroll
  for (int o = 8; o > 0; o >>= 1) {
    ex.x += __shfl_xor(ex.x, o, 64);
    ex.y += __shfl_xor(ex.y, o, 64);
    ex.z += __shfl_xor(ex.z, o, 64);
    ex.w += __shfl_xor(ex.w, o, 64);
  }
  float sm = (ex.x + ex.z) + (ex.y + ex.w);

  float ls = logf(sm);
  float4 o4;
  o4.x = (val.x - mx) - ls;
  o4.y = (val.y - mx) - ls;
  o4.z = (val.z - mx) - ls;
  o4.w = (val.w - mx) - ls;
  ((float4*)(out + (size_t)node * 64))[l16] = o4;
}

extern "C" void kernel_launch(void* const* d_in, const int* in_sizes, int n_in,
                              void* d_out, int out_size, void* d_ws, size_t ws_size,
                              hipStream_t stream) {
  const float* x   = (const float*)d_in[0];
  const int*   src = (const int*)d_in[1];
  const int*   dst = (const int*)d_in[2];
  const float* W1  = (const float*)d_in[3];
  const float* b1  = (const float*)d_in[4];
  const float* W2  = (const float*)d_in[5];
  const float* b2  = (const float*)d_in[6];
  float* out = (float*)d_out;
  int E = in_sizes[1];

  int* bcur   = (int*)d_ws;                         // NBKT
  int* packed = bcur + NBKT;                        // NBKT*BCAP
  int* cnt    = packed + (size_t)NBKT * BCAP;       // NROWS
  int* ssrc   = cnt + NROWS;                        // NROWS*64
  __half* mean1h = (__half*)(ssrc + (size_t)NROWS * 64); // NPAD*64 halves
  __half* xh   = mean1h + (size_t)NPAD * 64;             // NPAD*64 halves
  __half* gh   = xh + (size_t)NPAD * 64;                 // NPAD*64 halves

  hipMemsetAsync(bcur, 0, NBKT * sizeof(int), stream);
  bucketize_kernel<<<(E + CHUNK_A - 1) / CHUNK_A, 256, 0, stream>>>(
      src, dst, bcur, packed, x, xh, E);
  rows_kernel<<<NBKT, 256, 0, stream>>>(bcur, packed, cnt, ssrc);
  gather1_kernel<<<N_NODES / 16, 256, 0, stream>>>(xh, cnt, ssrc, mean1h);
  mlp_mfma_kernel<<<NPAD / 64, 256, 0, stream>>>(mean1h, W1, b1, W2, gh);
  gather2_kernel<<<N_NODES / 16, 256, 0, stream>>>(gh, cnt, ssrc, b2, out);
}

// Round 11
// 158.387 us; speedup vs baseline: 1.1244x; 1.0095x over previous
//
#include <hip/hip_runtime.h>
#include <hip/hip_fp16.h>

#define N_NODES 50000
#define EPS 1e-6f
#define NPAD 50048      // N rounded up to 64
#define CAP 64          // fixed per-node neighbor capacity (max real deg ~45, Poisson(16))

// ---- Two-pass radix build geometry (round-13) ----
#define NBKT 512        // buckets
#define NPB 98          // nodes per bucket; NBKT*NPB = 50176 >= NPAD
#define NROWS (NBKT * NPB)
#define BCAP 2048       // per-bucket edge capacity (= 1<<11); expected 1568, +12 sigma
#define CHUNK_A 3072    // edges per bucketize block -> 261 blocks (grid contract: >=256)
#define XH8 (N_NODES * 64 / 8)   // uint4-granules of the x->half conversion

// ---------------- Workspace layout (ints then halves) ----------------
// bcur   : NBKT ints      (zeroed each call)
// packed : NBKT*BCAP ints ((src<<8)|dlocal, grouped by bucket)
// cnt    : NROWS ints     (per-node degree)
// ssrc   : NROWS*64 ints  (fixed-stride per-node neighbor lists; gather2 input)
// mean1h : NPAD*64 halves (fp16 staging of layer-1 mean)
// xh     : NPAD*64 halves (fp16 staging of x)
// gh     : NPAD*64 halves (fp16 staging of layer-2 pre-gather features)
//
// NUMERICS CONTRACT (r18/19/21): absmax pinned 0.03125 (= 1 ulp of the
// bf16 output comparison). fp16 staging of gather operands (x, mean1, g)
// measured-invisible. f32-accum MFMA GEMMs with fp16 W1/W2/H (round-21,
// measured-invisible). Gather ADD SEQUENCE unchanged: groups-of-4
// (v0+v1)+(v2+v3) ascending, tail sequential, f32 after cvt.
//    mean = acc*dinv, dinv = 1/(deg+EPS); val = acc*dinv + b2;
//    softmax: lane-xor butterfly 8,4,2,1 then (x+z)+(y+w); (val-mx)-logf(sm).
// MFMA LAYOUT (round-21, verified): A/B frags contiguous-k, lane holds
// k=(lane>>4)*8+i via ds_read_b128 from row-major [m][k]/[n][k] tiles;
// C/D col=lane&15, row=(lane>>4)*4+reg. LDS strides%32banks==4.
// SCHEDULE CONTRACT (round-6): constant-trip k-loops with global loads
// carry #pragma unroll 1 (f32 path; MFMA loops are LDS-only, exempt).
// GATHER CONTRACT (round-8): NO per-edge LDS atomics in float gathers.
// GRID CONTRACT (round-9/20): build kernels >=256 blocks; gathers use
// per-tile grids — persistent grid-stride REGRESSED (round-20).
// BUILD CONTRACT (round-13): no scattered 4B global writes.
// FUSION CONTRACT (round-14 vs round-22): do NOT fuse gather behind a
// barrier-blocked GEMM (round-14, -8us). Fusing gather1 INTO rows_kernel
// (round-22) is different: gather is the trailing phase, all waves gather,
// indices come from the already-resident LDS row image; 8 waves/CU still
// saturate the ~64 MSHRs/CU (1 wave issues 128 lines).
// BATCH CONTRACT (round-16/17): branchless 16-load gather step; pad slots
// clamp index to row 0; uniform-predicate adds, compile-time indices.
// MACRO CONTRACT (round-17): multi-statement macros are do{...}while(0).
// PRECISION CONTRACT (round-18): fp16 staging (NOT bf16).
// CONCURRENCY MODEL (round-20): gathers are MSHR(~64/CU) x latency bound;
// scheduling tweaks are neutral; only fewer lines/row moves the floor.

#define COMP(v, j) ((j) == 0 ? (v).x : (j) == 1 ? (v).y : (j) == 2 ? (v).z : (v).w)

typedef _Float16 half8 __attribute__((ext_vector_type(8)));
typedef float floatx4 __attribute__((ext_vector_type(4)));

__device__ __forceinline__ float4 h4_to_f4(uint2 u) {
  __half2 h0 = *reinterpret_cast<__half2*>(&u.x);
  __half2 h1 = *reinterpret_cast<__half2*>(&u.y);
  float2 f0 = __half22float2(h0);
  float2 f1 = __half22float2(h1);
  float4 r; r.x = f0.x; r.y = f0.y; r.z = f1.x; r.w = f1.y;
  return r;
}

// ---- Pass A: partition edges into 512 buckets of 98 nodes ----
// (also converts x -> xh fp16 staging, grid-stride)
__global__ __launch_bounds__(256) void bucketize_kernel(
    const int* __restrict__ src, const int* __restrict__ dst,
    int* __restrict__ bcur, int* __restrict__ packed,
    const float* __restrict__ x, __half* __restrict__ xh, int E) {
  __shared__ int lcnt[NBKT];
  __shared__ int lbase[NBKT];
  int t = threadIdx.x;

  for (int i = blockIdx.x * 256 + t; i < XH8; i += gridDim.x * 256) {
    float4 a = ((const float4*)x)[2 * i];
    float4 b = ((const float4*)x)[2 * i + 1];
    __half2 h0 = __floats2half2_rn(a.x, a.y);
    __half2 h1 = __floats2half2_rn(a.z, a.w);
    __half2 h2 = __floats2half2_rn(b.x, b.y);
    __half2 h3 = __floats2half2_rn(b.z, b.w);
    uint4 o;
    o.x = *(unsigned int*)&h0; o.y = *(unsigned int*)&h1;
    o.z = *(unsigned int*)&h2; o.w = *(unsigned int*)&h3;
    ((uint4*)xh)[i] = o;
  }

  lcnt[t] = 0; lcnt[t + 256] = 0;
  __syncthreads();
  int base = blockIdx.x * CHUNK_A;
  int end = base + CHUNK_A; if (end > E) end = E;
  for (int e = base + t; e < end; e += 256) atomicAdd(&lcnt[dst[e] / NPB], 1);
  __syncthreads();
  {
    int c0 = lcnt[t], c1 = lcnt[t + 256];
    lbase[t]       = c0 ? atomicAdd(&bcur[t], c0) : 0;
    lbase[t + 256] = c1 ? atomicAdd(&bcur[t + 256], c1) : 0;
    lcnt[t] = 0; lcnt[t + 256] = 0;
  }
  __syncthreads();
  for (int e = base + t; e < end; e += 256) {
    int d = dst[e];
    int b = d / NPB;
    int pos = lbase[b] + atomicAdd(&lcnt[b], 1);
    if (pos < BCAP)
      packed[(b << 11) + pos] = (src[e] << 8) | (d - b * NPB);
  }
}

// Quad add in contract order (per component: one quad at a time, ascending).
#define QADD(V0, V1, V2, V3) do {                                         \
    acc.x += ((V0).x + (V1).x) + ((V2).x + (V3).x);                       \
    acc.y += ((V0).y + (V1).y) + ((V2).y + (V3).y);                       \
    acc.z += ((V0).z + (V1).z) + ((V2).z + (V3).z);                       \
    acc.w += ((V0).w + (V1).w) + ((V2).w + (V3).w);                       \
  } while (0)

#define ADD1(V) do {                                                      \
    acc.x += (V).x; acc.y += (V).y; acc.z += (V).z; acc.w += (V).w;       \
  } while (0)

// Row-load + contract-order accumulate given index array s[16] and rem.
#define GATHER_BODY_H(SRCPTR)                                             \
  do {                                                                    \
    uint2 v[16];                                                          \
    _Pragma("unroll")                                                     \
    for (int j = 0; j < 16; j++)                                          \
      v[j] = ((const uint2*)((SRCPTR) + (size_t)s[j] * 64))[l16];         \
    int rq = rem >> 2, rr = rem & 3;                                      \
    _Pragma("unroll")                                                     \
    for (int q = 0; q < 4; q++) {                                         \
      if (q < rq) {                                                       \
        float4 f0 = h4_to_f4(v[4 * q]);                                   \
        float4 f1 = h4_to_f4(v[4 * q + 1]);                               \
        float4 f2 = h4_to_f4(v[4 * q + 2]);                               \
        float4 f3 = h4_to_f4(v[4 * q + 3]);                               \
        QADD(f0, f1, f2, f3);                                             \
      }                                                                   \
    }                                                                     \
    _Pragma("unroll")                                                     \
    for (int q = 0; q < 4; q++) {                                         \
      if (q == rq && rr > 0) {                                            \
        float4 f0 = h4_to_f4(v[4 * q]);                                   \
        ADD1(f0);                                                         \
        if (rr > 1) { float4 f1 = h4_to_f4(v[4 * q + 1]); ADD1(f1); }     \
        if (rr > 2) { float4 f2 = h4_to_f4(v[4 * q + 2]); ADD1(f2); }     \
      }                                                                   \
    }                                                                     \
  } while (0)

// ---- Pass B + gather1 fused: build rows, store ssrc/cnt, then gather
// means for this bucket's nodes with indices read from the LDS row image.
__global__ __launch_bounds__(256) void rows_gather1_kernel(
    const int* __restrict__ bcur, const int* __restrict__ packed,
    int* __restrict__ cnt, int* __restrict__ ssrc,
    const __half* __restrict__ xh, __half* __restrict__ mean1h) {
  __shared__ int lout[NPB * 64];
  __shared__ int lcnt[NPB];
  int t = threadIdx.x;
  int b = blockIdx.x;
  if (t < NPB) lcnt[t] = 0;
  __syncthreads();
  int count = bcur[b]; if (count > BCAP) count = BCAP;
  const int* pk = packed + (b << 11);
  for (int i = t; i < count; i += 256) {
    int p = pk[i];
    int dl = p & 0xff;
    int pos = atomicAdd(&lcnt[dl], 1);
    if (pos < CAP) lout[(dl << 6) + pos] = p >> 8;
  }
  __syncthreads();
  // ssrc/cnt stores: fire-and-forget, drain under the gather phase
  {
    int4* d4 = (int4*)(ssrc + (size_t)b * (NPB * 64));
    const int4* s4 = (const int4*)lout;
    for (int i = t; i < NPB * 16; i += 256) d4[i] = s4[i];
    if (t < NPB) {
      int c = lcnt[t]; if (c > CAP) c = CAP;
      cnt[b * NPB + t] = c;
    }
  }
  // gather phase: subgroup sg = t>>4 handles dl = sg, sg+16, ...
  int sg = t >> 4;
  int l16 = t & 15;
  for (int dl = sg; dl < NPB; dl += 16) {
    int node = b * NPB + dl;
    if (node >= N_NODES) continue;
    int deg = lcnt[dl]; if (deg > CAP) deg = CAP;
    const int* lrow = &lout[dl << 6];
    float4 acc = {0.f, 0.f, 0.f, 0.f};
    for (int base = 0; base < deg; base += 16) {
      int rem = deg - base; if (rem > 16) rem = 16;
      int s[16];
#pragma unroll
      for (int j = 0; j < 16; j++) s[j] = lrow[base + j];  // LDS broadcast
#pragma unroll
      for (int j = 0; j < 16; j++) { if (j >= rem) s[j] = 0; }
      GATHER_BODY_H(xh);
    }
    float dinv = 1.0f / ((float)deg + EPS);
    __half2 p0 = __floats2half2_rn(acc.x * dinv, acc.y * dinv);
    __half2 p1 = __floats2half2_rn(acc.z * dinv, acc.w * dinv);
    uint2 o;
    o.x = *(unsigned int*)&p0; o.y = *(unsigned int*)&p1;
    ((uint2*)(mean1h + (size_t)node * 64))[l16] = o;
  }
}

// ---- MFMA MLP: GEMM1(64x64x128)+relu -> GEMM2(64x128x64), fp16 out ----
__global__ __launch_bounds__(256) void mlp_mfma_kernel(
    const __half* __restrict__ mean1h, const float* __restrict__ W1,
    const float* __restrict__ b1, const float* __restrict__ W2,
    __half* __restrict__ gh) {
  // LDS carve: sM[64][72] 9216B | sW1T[128][72] 18432B | sH[64][136] 17408B
  //            | sW2T[64][136] 17408B = 62464B. sG[64][64] aliases sM.
  __shared__ __align__(16) char smem[62464];
  __half (*sM)[72]    = (__half(*)[72])smem;
  __half (*sW1T)[72]  = (__half(*)[72])(smem + 9216);
  __half (*sH)[136]   = (__half(*)[136])(smem + 27648);
  __half (*sW2T)[136] = (__half(*)[136])(smem + 45056);
  __half (*sG)[64]    = (__half(*)[64])smem;

  int t = threadIdx.x;
  int row0 = blockIdx.x * 64;

  {  // stage mean rows (fp16 as-is): 512 uint4
    const uint4* M4 = (const uint4*)(mean1h + (size_t)row0 * 64);
#pragma unroll
    for (int i = 0; i < 2; i++) {
      int idx = t + 256 * i;
      uint4 v = M4[idx];
      *(uint4*)&sM[idx >> 3][(idx & 7) * 8] = v;
    }
  }
#pragma unroll
  for (int i = 0; i < 8; i++) {  // W1[64][128] f32 -> sW1T[c][k] fp16
    int idx = t + 256 * i;
    int k = idx >> 5, c4 = (idx & 31) * 4;
    float4 w = *(const float4*)(W1 + (size_t)k * 128 + c4);
    sW1T[c4 + 0][k] = __float2half(w.x);
    sW1T[c4 + 1][k] = __float2half(w.y);
    sW1T[c4 + 2][k] = __float2half(w.z);
    sW1T[c4 + 3][k] = __float2half(w.w);
  }
#pragma unroll
  for (int i = 0; i < 8; i++) {  // W2[128][64] f32 -> sW2T[c][k] fp16
    int idx = t + 256 * i;
    int k = idx >> 4, c4 = (idx & 15) * 4;
    float4 w = *(const float4*)(W2 + (size_t)k * 64 + c4);
    sW2T[c4 + 0][k] = __float2half(w.x);
    sW2T[c4 + 1][k] = __float2half(w.y);
    sW2T[c4 + 2][k] = __float2half(w.z);
    sW2T[c4 + 3][k] = __float2half(w.w);
  }
  __syncthreads();

  int l = t & 63, wv = t >> 6;
  int l16 = l & 15, lg = l >> 4;

  {  // GEMM1: wave wv owns col-tiles {2wv,2wv+1} x row-tiles 0..3, K=64
    floatx4 acc[4][2];
#pragma unroll
    for (int tc = 0; tc < 2; tc++) {
      float bias = b1[(2 * wv + tc) * 16 + l16];
#pragma unroll
      for (int tr = 0; tr < 4; tr++)
        acc[tr][tc] = (floatx4){bias, bias, bias, bias};
    }
#pragma unroll
    for (int kb = 0; kb < 2; kb++) {
      half8 a[4], bf[2];
#pragma unroll
      for (int tr = 0; tr < 4; tr++)
        a[tr] = *(const half8*)&sM[tr * 16 + l16][kb * 32 + lg * 8];
#pragma unroll
      for (int tc = 0; tc < 2; tc++)
        bf[tc] = *(const half8*)&sW1T[(2 * wv + tc) * 16 + l16][kb * 32 + lg * 8];
#pragma unroll
      for (int tc = 0; tc < 2; tc++)
#pragma unroll
        for (int tr = 0; tr < 4; tr++)
          acc[tr][tc] = __builtin_amdgcn_mfma_f32_16x16x32_f16(
              a[tr], bf[tc], acc[tr][tc], 0, 0, 0);
    }
#pragma unroll
    for (int tc = 0; tc < 2; tc++)
#pragma unroll
      for (int tr = 0; tr < 4; tr++)
#pragma unroll
        for (int r = 0; r < 4; r++) {
          float h = fmaxf(acc[tr][tc][r], 0.f);
          sH[tr * 16 + lg * 4 + r][(2 * wv + tc) * 16 + l16] = __float2half(h);
        }
  }
  __syncthreads();

  {  // GEMM2: wave wv owns row-tile wv x col-tiles 0..3, K=128
    floatx4 acc[4];
#pragma unroll
    for (int tc = 0; tc < 4; tc++) acc[tc] = (floatx4){0.f, 0.f, 0.f, 0.f};
    half8 a[4];
#pragma unroll
    for (int kb = 0; kb < 4; kb++)
      a[kb] = *(const half8*)&sH[wv * 16 + l16][kb * 32 + lg * 8];
#pragma unroll
    for (int tc = 0; tc < 4; tc++) {
#pragma unroll
      for (int kb = 0; kb < 4; kb++) {
        half8 bf = *(const half8*)&sW2T[tc * 16 + l16][kb * 32 + lg * 8];
        acc[tc] = __builtin_amdgcn_mfma_f32_16x16x32_f16(a[kb], bf, acc[tc], 0, 0, 0);
      }
    }
    // sG aliases sM — sM is dead after GEMM1's closing barrier.
#pragma unroll
    for (int tc = 0; tc < 4; tc++)
#pragma unroll
      for (int r = 0; r < 4; r++)
        sG[wv * 16 + lg * 4 + r][tc * 16 + l16] = __float2half(acc[tc][r]);
  }
  __syncthreads();

  // coalesced copy sG -> gh (8B granules), guard tail rows
#pragma unroll
  for (int i = 0; i < 4; i++) {
    int idx = t + 256 * i;            // 0..1023
    int row = idx >> 4, c4 = (idx & 15) * 4;
    if (row0 + row < N_NODES)
      *(uint2*)(gh + (size_t)(row0 + row) * 64 + c4) = *(uint2*)&sG[row][c4];
  }
}

// ---- Gather 2 + bias + log_softmax (fp16 source, f32 math) ----
__global__ __launch_bounds__(256) void gather2_kernel(
    const __half* __restrict__ gh, const int* __restrict__ cnt,
    const int* __restrict__ ssrc, const float* __restrict__ b2,
    float* __restrict__ out) {
  int t = threadIdx.x;
  int lane = t & 63;
  int sub = lane >> 4;
  int l16 = lane & 15;
  int node = blockIdx.x * 16 + ((t >> 6) << 2) + sub;
  int b = node << 6;
  int e = b + cnt[node];
  float4 acc = {0.f, 0.f, 0.f, 0.f};
  for (int base = b; base < e; base += 16) {
    int rem = e - base; if (rem > 16) rem = 16;
    int s[16];
#pragma unroll
    for (int j = 0; j < 16; j++) s[j] = ssrc[base + j];
#pragma unroll
    for (int j = 0; j < 16; j++) { if (j >= rem) s[j] = 0; }
    GATHER_BODY_H(gh);
  }
  float dinv = 1.0f / ((float)(e - b) + EPS);
  float4 b2v = ((const float4*)b2)[l16];
  float4 val;
  val.x = acc.x * dinv + b2v.x;
  val.y = acc.y * dinv + b2v.y;
  val.z = acc.z * dinv + b2v.z;
  val.w = acc.w * dinv + b2v.w;

  float4 m = val;
#pragma unroll
  for (int o = 8; o > 0; o >>= 1) {
    m.x = fmaxf(m.x, __shfl_xor(m.x, o, 64));
    m.y = fmaxf(m.y, __shfl_xor(m.y, o, 64));
    m.z = fmaxf(m.z, __shfl_xor(m.z, o, 64));
    m.w = fmaxf(m.w, __shfl_xor(m.w, o, 64));
  }
  float mx = fmaxf(fmaxf(m.x, m.z), fmaxf(m.y, m.w));

  float4 ex;
  ex.x = __expf(val.x - mx);
  ex.y = __expf(val.y - mx);
  ex.z = __expf(val.z - mx);
  ex.w = __expf(val.w - mx);
#pragma unroll
  for (int o = 8; o > 0; o >>= 1) {
    ex.x += __shfl_xor(ex.x, o, 64);
    ex.y += __shfl_xor(ex.y, o, 64);
    ex.z += __shfl_xor(ex.z, o, 64);
    ex.w += __shfl_xor(ex.w, o, 64);
  }
  float sm = (ex.x + ex.z) + (ex.y + ex.w);

  float ls = logf(sm);
  float4 o4;
  o4.x = (val.x - mx) - ls;
  o4.y = (val.y - mx) - ls;
  o4.z = (val.z - mx) - ls;
  o4.w = (val.w - mx) - ls;
  ((float4*)(out + (size_t)node * 64))[l16] = o4;
}

extern "C" void kernel_launch(void* const* d_in, const int* in_sizes, int n_in,
                              void* d_out, int out_size, void* d_ws, size_t ws_size,
                              hipStream_t stream) {
  const float* x   = (const float*)d_in[0];
  const int*   src = (const int*)d_in[1];
  const int*   dst = (const int*)d_in[2];
  const float* W1  = (const float*)d_in[3];
  const float* b1  = (const float*)d_in[4];
  const float* W2  = (const float*)d_in[5];
  const float* b2  = (const float*)d_in[6];
  float* out = (float*)d_out;
  int E = in_sizes[1];

  int* bcur   = (int*)d_ws;                         // NBKT
  int* packed = bcur + NBKT;                        // NBKT*BCAP
  int* cnt    = packed + (size_t)NBKT * BCAP;       // NROWS
  int* ssrc   = cnt + NROWS;                        // NROWS*64
  __half* mean1h = (__half*)(ssrc + (size_t)NROWS * 64); // NPAD*64 halves
  __half* xh   = mean1h + (size_t)NPAD * 64;             // NPAD*64 halves
  __half* gh   = xh + (size_t)NPAD * 64;                 // NPAD*64 halves

  hipMemsetAsync(bcur, 0, NBKT * sizeof(int), stream);
  bucketize_kernel<<<(E + CHUNK_A - 1) / CHUNK_A, 256, 0, stream>>>(
      src, dst, bcur, packed, x, xh, E);
  rows_gather1_kernel<<<NBKT, 256, 0, stream>>>(bcur, packed, cnt, ssrc, xh, mean1h);
  mlp_mfma_kernel<<<NPAD / 64, 256, 0, stream>>>(mean1h, W1, b1, W2, gh);
  gather2_kernel<<<N_NODES / 16, 256, 0, stream>>>(gh, cnt, ssrc, b2, out);
}